// Round 4
// baseline (1416.622 us; speedup 1.0000x reference)
//
#include <hip/hip_runtime.h>
#include <hip/hip_bf16.h>

#define M_PTS 100000
#define KN 27
#define CS 96
#define NC 13

// flat output offsets (f32 elements), return order:
// logits[M,13], bdy[M,1], affinity[M,1,27], refined[M,64], neighbor[M,27], mask[M,27]
#define OFF_LOGITS 0ull
#define OFF_BDY    1300000ull
#define OFF_AFF    1400000ull
#define OFF_RF     4100000ull
#define OFF_NBR    10500000ull
#define OFF_MASK   13200000ull

typedef float f4 __attribute__((ext_vector_type(4)));
typedef unsigned short u16x8 __attribute__((ext_vector_type(8)));

__device__ __forceinline__ float wave_red_sum(float v) {
#pragma unroll
  for (int o = 32; o > 0; o >>= 1) v += __shfl_xor(v, o, 64);
  return v;
}
__device__ __forceinline__ float wave_red_max(float v) {
#pragma unroll
  for (int o = 32; o > 0; o >>= 1) v = fmaxf(v, __shfl_xor(v, o, 64));
  return v;
}
__device__ __forceinline__ float bf2f(unsigned short u) {
  union { unsigned int i; float f; } x;
  x.i = ((unsigned int)u) << 16;
  return x.f;
}
__device__ __forceinline__ bool nbr_is64(const void* nbrv) {
  const int* w = (const int*)nbrv;
  bool is64 = true;
#pragma unroll
  for (int j = 1; j < 64; j += 2) is64 = is64 && (w[j] == 0);
  return is64;
}
__device__ __forceinline__ long long nbr_at(const void* nbrv, bool is64, size_t i) {
  return is64 ? ((const long long*)nbrv)[i] : (long long)((const int*)nbrv)[i];
}

// k1: per point m (one wave each): Q_geo/U/P -> ws (bf16), bdy/neighbor/mask -> out (f32).
__global__ __launch_bounds__(256) void k1(const float* __restrict__ geo,
                                          const int* __restrict__ coords,
                                          const void* __restrict__ nbrv,
                                          const float* __restrict__ Wgeo,
                                          const float* __restrict__ gamma,
                                          const float* __restrict__ beta,
                                          const float* __restrict__ Wbdy,
                                          const float* __restrict__ bbdy,
                                          const float* __restrict__ Wq,
                                          const float* __restrict__ Wk,
                                          const float* __restrict__ pos,
                                          __hip_bfloat16* __restrict__ Qg,
                                          __hip_bfloat16* __restrict__ U,
                                          __hip_bfloat16* __restrict__ P,
                                          float* __restrict__ out) {
  __shared__ float sWgeo[4096];
  __shared__ float sWq[4096];
  __shared__ float sWkT[4096];   // sWkT[d*64+c] = Wk[c][d]
  __shared__ float sPos[27 * 65];
  const int tid = threadIdx.x;
  for (int i = tid; i < 4096; i += 256) {
    sWgeo[i] = Wgeo[i];
    sWq[i] = Wq[i];
    sWkT[i] = Wk[(i & 63) * 64 + (i >> 6)];
  }
  for (int i = tid; i < 27 * 64; i += 256) sPos[(i >> 6) * 65 + (i & 63)] = pos[i];
  const bool is64 = nbr_is64(nbrv);
  __syncthreads();

  const int lane = tid & 63;
  const int wid = tid >> 6;
  const float gam = gamma[lane], bet = beta[lane], wb = Wbdy[lane], bb = bbdy[0];

  for (int m = blockIdx.x * 4 + wid; m < M_PTS; m += gridDim.x * 4) {
    float acc = 0.f;
    const f4* grow = (const f4*)(geo + (size_t)m * 64);
#pragma unroll
    for (int c4 = 0; c4 < 16; ++c4) {
      f4 g4 = grow[c4];
      acc = fmaf(g4.x, sWgeo[(c4 * 4 + 0) * 64 + lane], acc);
      acc = fmaf(g4.y, sWgeo[(c4 * 4 + 1) * 64 + lane], acc);
      acc = fmaf(g4.z, sWgeo[(c4 * 4 + 2) * 64 + lane], acc);
      acc = fmaf(g4.w, sWgeo[(c4 * 4 + 3) * 64 + lane], acc);
    }
    const float mu = wave_red_sum(acc) * (1.f / 64.f);
    const float dv = acc - mu;
    const float var = wave_red_sum(dv * dv) * (1.f / 64.f);
    const float q = fmaxf(dv * rsqrtf(var + 1e-5f) * gam + bet, 0.f);
    Qg[(size_t)m * 64 + lane] = __float2bfloat16(q);

    const float bsum = wave_red_sum(q * wb);
    if (lane == 0) out[OFF_BDY + (size_t)m] = bsum + bb;

    float qp = 0.f;
#pragma unroll
    for (int c = 0; c < 64; ++c) qp = fmaf(__shfl(q, c, 64), sWq[c * 64 + lane], qp);

    float u = 0.f, p = 0.f;
#pragma unroll
    for (int dd = 0; dd < 64; ++dd) {
      const float qd = __shfl(qp, dd, 64);
      u = fmaf(qd, sWkT[dd * 64 + lane], u);
      if (lane < KN) p = fmaf(qd, sPos[lane * 65 + dd], p);
    }
    U[(size_t)m * 64 + lane] = __float2bfloat16(u);
    if (lane < KN) P[(size_t)m * KN + lane] = __float2bfloat16(p);

    if (lane < KN) {
      const size_t ni = (size_t)m * KN + lane;
      const long long nk = nbr_at(nbrv, is64, ni);
      const int dx = coords[nk * 3 + 0] - coords[m * 3 + 0];
      const int dy = coords[nk * 3 + 1] - coords[m * 3 + 1];
      const int dz = coords[nk * 3 + 2] - coords[m * 3 + 2];
      const int mx3 = max(max(abs(dx), abs(dy)), abs(dz));
      out[OFF_NBR + ni] = (float)nk;
      out[OFF_MASK + ni] = (mx3 <= 1) ? 1.f : 0.f;
    }
  }
}

// k2: per point m (one wave each): attn logits via U.Qg[nk] + P, softmax,
//     weighted sem sum, r1 = s@Wv, rf = r1@Wout + b, logits = rf@Wcls + b.
__global__ __launch_bounds__(256) void k2(const float* __restrict__ sem,
                                          const int* __restrict__ coords,
                                          const void* __restrict__ nbrv,
                                          const float* __restrict__ Wv,
                                          const float* __restrict__ Wout,
                                          const float* __restrict__ bout,
                                          const float* __restrict__ Wcls,
                                          const float* __restrict__ bcls,
                                          const __hip_bfloat16* __restrict__ Qg,
                                          const __hip_bfloat16* __restrict__ U,
                                          const __hip_bfloat16* __restrict__ P,
                                          float* __restrict__ out) {
  __shared__ float sWv[CS * 64];
  __shared__ float sWout[4096];
  __shared__ float sWcls[64 * NC];
  const int tid = threadIdx.x;
  for (int i = tid; i < CS * 64; i += 256) sWv[i] = Wv[i];
  for (int i = tid; i < 4096; i += 256) sWout[i] = Wout[i];
  for (int i = tid; i < 64 * NC; i += 256) sWcls[i] = Wcls[i];
  const bool is64 = nbr_is64(nbrv);
  __syncthreads();

  const int lane = tid & 63;
  const int wid = tid >> 6;
  const float bo = bout[lane];
  const float bc = (lane < NC) ? bcls[lane] : 0.f;
  const int cls_col = (lane < NC) ? lane : 0;

  for (int m = blockIdx.x * 4 + wid; m < M_PTS; m += gridDim.x * 4) {
    const int c0 = coords[m * 3 + 0], c1 = coords[m * 3 + 1], c2 = coords[m * 3 + 2];
    int nki = 0;
    float logit = -1e30f;
    if (lane < KN) {
      const long long nk = nbr_at(nbrv, is64, (size_t)m * KN + lane);
      nki = (int)nk;
      const int dx = coords[nk * 3 + 0] - c0;
      const int dy = coords[nk * 3 + 1] - c1;
      const int dz = coords[nk * 3 + 2] - c2;
      if (max(max(abs(dx), abs(dy)), abs(dz)) <= 1) {
        const int pidx = (dx + 1) * 9 + (dy + 1) * 3 + (dz + 1);
        const float pv = __bfloat162float(P[(size_t)m * KN + pidx]);
        const u16x8* qr = (const u16x8*)(Qg + (size_t)nk * 64);
        const u16x8* ur = (const u16x8*)(U + (size_t)m * 64);
        float dot = 0.f;
#pragma unroll
        for (int i = 0; i < 8; ++i) {
          const u16x8 qa = qr[i];
          const u16x8 ub = ur[i];
#pragma unroll
          for (int j = 0; j < 8; ++j) dot = fmaf(bf2f(qa[j]), bf2f(ub[j]), dot);
        }
        logit = (dot + pv) * 0.125f;
      } else {
        logit = -10000.0f;
      }
    }
    const float mx = wave_red_max(logit);
    const float e = (lane < KN) ? __expf(logit - mx) : 0.f;
    const float ssum = wave_red_sum(e);
    const float a = e / ssum;
    if (lane < KN) out[OFF_AFF + (size_t)m * KN + lane] = a;

    float s_lo = sem[(size_t)m * CS + lane];
    float s_hi = (lane < 32) ? sem[(size_t)m * CS + 64 + lane] : 0.f;
    unsigned long long mb = __ballot(lane < KN && a > 0.f);
    while (mb) {
      const int k = __ffsll(mb) - 1;
      mb &= mb - 1;
      const float ak = __shfl(a, k, 64);
      const int nkk = __shfl(nki, k, 64);
      s_lo = fmaf(ak, sem[(size_t)nkk * CS + lane], s_lo);
      if (lane < 32) s_hi = fmaf(ak, sem[(size_t)nkk * CS + 64 + lane], s_hi);
    }
    float r1 = 0.f;
#pragma unroll
    for (int c = 0; c < 64; ++c) r1 = fmaf(__shfl(s_lo, c, 64), sWv[c * 64 + lane], r1);
#pragma unroll
    for (int c = 0; c < 32; ++c) r1 = fmaf(__shfl(s_hi, c, 64), sWv[(64 + c) * 64 + lane], r1);
    float rf = bo;
#pragma unroll
    for (int c = 0; c < 64; ++c) rf = fmaf(__shfl(r1, c, 64), sWout[c * 64 + lane], rf);
    out[OFF_RF + (size_t)m * 64 + lane] = rf;

    float lg = bc;
#pragma unroll
    for (int dd = 0; dd < 64; ++dd)
      lg = fmaf(__shfl(rf, dd, 64), sWcls[dd * NC + cls_col], lg);
    if (lane < NC) out[OFF_LOGITS + (size_t)m * NC + lane] = lg;
  }
}

extern "C" void kernel_launch(void* const* d_in, const int* in_sizes, int n_in,
                              void* d_out, int out_size, void* d_ws, size_t ws_size,
                              hipStream_t stream) {
  const float* geo = (const float*)d_in[0];
  const float* sem = (const float*)d_in[1];
  const int* coords = (const int*)d_in[2];
  const void* nbrv = (const void*)d_in[3];
  const float* Wgeo = (const float*)d_in[4];
  const float* gamma = (const float*)d_in[5];
  const float* beta = (const float*)d_in[6];
  const float* Wbdy = (const float*)d_in[7];
  const float* bbdy = (const float*)d_in[8];
  const float* Wq = (const float*)d_in[9];
  const float* Wk = (const float*)d_in[10];
  const float* Wv = (const float*)d_in[11];
  const float* pos = (const float*)d_in[12];
  const float* Wout = (const float*)d_in[13];
  const float* bout = (const float*)d_in[14];
  const float* Wcls = (const float*)d_in[15];
  const float* bcls = (const float*)d_in[16];

  // bf16 workspace: Qg [6.4M], U [6.4M], P [2.7M] -> 31 MB total
  __hip_bfloat16* Qg = (__hip_bfloat16*)d_ws;
  __hip_bfloat16* U = Qg + (size_t)M_PTS * 64;
  __hip_bfloat16* P = U + (size_t)M_PTS * 64;

  float* out = (float*)d_out;

  k1<<<1024, 256, 0, stream>>>(geo, coords, nbrv, Wgeo, gamma, beta, Wbdy, bbdy,
                               Wq, Wk, pos, Qg, U, P, out);
  k2<<<1024, 256, 0, stream>>>(sem, coords, nbrv, Wv, Wout, bout, Wcls, bcls,
                               Qg, U, P, out);
}

// Round 6
// 446.935 us; speedup vs baseline: 3.1696x; 3.1696x over previous
//
#include <hip/hip_runtime.h>
#include <hip/hip_bf16.h>

#define M_PTS 100000
#define KN 27
#define CS 96
#define NC 13

// flat output offsets (f32 elements), return order:
// logits[M,13], bdy[M,1], affinity[M,1,27], refined[M,64], neighbor[M,27], mask[M,27]
#define OFF_LOGITS 0ull
#define OFF_BDY    1300000ull
#define OFF_AFF    1400000ull
#define OFF_RF     4100000ull
#define OFF_NBR    10500000ull
#define OFF_MASK   13200000ull

// ws layout (units = shorts/bf16)
#define WS_QG   0ull                    // [M][64] bf16
#define WS_U    6400000ull              // [M][64] bf16
#define WS_P    12800000ull             // [M][27] bf16
#define WS_WGEO 15500000ull             // [64][72]  WgeoB[d][c] = Wgeo[c][d]
#define WS_WQK  (WS_WGEO + 4608ull)     // [64][72]  WqkB[d][c]  = sum_t Wq[c][t]Wk[d][t]
#define WS_WPOS (WS_WQK + 4608ull)      // [32][72]  rows 0-26: sum_t Wq[c][t]pos[j][t]; row 27: Wbdy
#define WS_W1   (WS_WPOS + 2304ull)     // [64][104] W1B[d][s] = sum_t Wv[s][t]Wout[t][d]
#define WS_W2   (WS_W1 + 6656ull)       // [16][104] W2B[j][s] = sum_d W1[s][d]Wcls[d][j]
#define WS_B2   (WS_W2 + 1664ull)       // f32[16]: b2[j] = bout@Wcls[:,j] + bcls[j]

typedef float f4 __attribute__((ext_vector_type(4)));
typedef float f32x4 __attribute__((ext_vector_type(4)));
typedef short bf16x8 __attribute__((ext_vector_type(8)));

__device__ __forceinline__ short f2bf(float f) {
  union { float f; unsigned int u; } x; x.f = f;
  unsigned int r = x.u + 0x7fffu + ((x.u >> 16) & 1u);
  return (short)(r >> 16);
}
__device__ __forceinline__ float bf2f(unsigned short u) {
  union { unsigned int i; float f; } x; x.i = ((unsigned int)u) << 16;
  return x.f;
}
__device__ __forceinline__ bool nbr_is64(const void* nbrv) {
  const int* w = (const int*)nbrv;
  bool is64 = true;
#pragma unroll
  for (int j = 1; j < 64; j += 2) is64 = is64 && (w[j] == 0);
  return is64;
}
__device__ __forceinline__ long long nbr_at(const void* nbrv, bool is64, size_t i) {
  return is64 ? ((const long long*)nbrv)[i] : (long long)((const int*)nbrv)[i];
}

// ---------------- k0: fused-weight precompute (1 block) ----------------
__global__ __launch_bounds__(1024) void k0(const float* __restrict__ Wgeo,
                                           const float* __restrict__ Wbdy,
                                           const float* __restrict__ Wq,
                                           const float* __restrict__ Wk,
                                           const float* __restrict__ Wv,
                                           const float* __restrict__ pos,
                                           const float* __restrict__ Wout,
                                           const float* __restrict__ bout,
                                           const float* __restrict__ Wcls,
                                           const float* __restrict__ bcls,
                                           short* __restrict__ ws) {
  __shared__ float V[64 * NC];
  const int tid = threadIdx.x;
  for (int i = tid; i < 4096; i += 1024) {
    const int d = i >> 6, c = i & 63;
    ws[WS_WGEO + d * 72 + c] = f2bf(Wgeo[c * 64 + d]);
  }
  for (int i = tid; i < 4096; i += 1024) {
    const int d = i >> 6, c = i & 63;
    float s = 0.f;
#pragma unroll 8
    for (int t = 0; t < 64; ++t) s = fmaf(Wq[c * 64 + t], Wk[d * 64 + t], s);
    ws[WS_WQK + d * 72 + c] = f2bf(s);
  }
  for (int i = tid; i < 2048; i += 1024) {
    const int j = i >> 6, c = i & 63;
    float s = 0.f;
    if (j < 27) {
#pragma unroll 8
      for (int t = 0; t < 64; ++t) s = fmaf(Wq[c * 64 + t], pos[j * 64 + t], s);
    } else if (j == 27) {
      s = Wbdy[c];
    }
    ws[WS_WPOS + j * 72 + c] = f2bf(s);
  }
  for (int i = tid; i < 6144; i += 1024) {
    const int d = i / 96, s = i % 96;
    float a = 0.f;
#pragma unroll 8
    for (int t = 0; t < 64; ++t) a = fmaf(Wv[s * 64 + t], Wout[t * 64 + d], a);
    ws[WS_W1 + d * 104 + s] = f2bf(a);
  }
  for (int i = tid; i < 64 * NC; i += 1024) {
    const int t = i / NC, j = i % NC;
    float a = 0.f;
#pragma unroll 8
    for (int d = 0; d < 64; ++d) a = fmaf(Wout[t * 64 + d], Wcls[d * NC + j], a);
    V[i] = a;
  }
  __syncthreads();
  for (int i = tid; i < 16 * 96; i += 1024) {
    const int j = i / 96, s = i % 96;
    float a = 0.f;
    if (j < NC) {
#pragma unroll 8
      for (int t = 0; t < 64; ++t) a = fmaf(Wv[s * 64 + t], V[t * NC + j], a);
    }
    ws[WS_W2 + j * 104 + s] = f2bf(a);
  }
  float* b2 = (float*)(ws + WS_B2);
  for (int i = tid; i < 16; i += 1024) {
    float a = 0.f;
    if (i < NC) {
      for (int d = 0; d < 64; ++d) a = fmaf(bout[d], Wcls[d * NC + i], a);
      a += bcls[i];
    }
    b2[i] = a;
  }
}

// ---------------- k1: 64-pt tile MFMA: geo@Wgeo -> LN/ReLU -> q; U=q@Wqk; [P|bdy]=q@Wpos ----------------
__global__ __launch_bounds__(256) void k1(const float* __restrict__ geo,
                                          const int* __restrict__ coords,
                                          const void* __restrict__ nbrv,
                                          const float* __restrict__ gamma,
                                          const float* __restrict__ beta,
                                          const float* __restrict__ bbdy,
                                          const short* __restrict__ ws,
                                          short* __restrict__ Qg,
                                          short* __restrict__ U,
                                          short* __restrict__ P,
                                          float* __restrict__ out) {
  __shared__ short sX[4608];   // [64][72]  X-tile then U staging
  __shared__ short sQ[4608];   // [64][72]  q tile
  __shared__ short sWg[4608];
  __shared__ short sWqk[4608];
  __shared__ short sWp[2304];
  const int tid = threadIdx.x;
  // weight images global->LDS (coalesced 16B)
  {
    const bf16x8* a = (const bf16x8*)(ws + WS_WGEO);
    const bf16x8* b = (const bf16x8*)(ws + WS_WQK);
    const bf16x8* c = (const bf16x8*)(ws + WS_WPOS);
    for (int i = tid; i < 576; i += 256) ((bf16x8*)sWg)[i] = a[i];
    for (int i = tid; i < 576; i += 256) ((bf16x8*)sWqk)[i] = b[i];
    for (int i = tid; i < 288; i += 256) ((bf16x8*)sWp)[i] = c[i];
  }
  const int m0 = blockIdx.x * 64;
  // X tile: thread t -> row t>>2, col-quarter t&3
  {
    const int r = tid >> 2, qq = tid & 3;
    const int m = min(m0 + r, M_PTS - 1);
    const f4* g = (const f4*)(geo + (size_t)m * 64 + qq * 16);
    const f4 a = g[0], b = g[1], c = g[2], d = g[3];
    bf16x8 lo, hi;
    lo[0]=f2bf(a.x); lo[1]=f2bf(a.y); lo[2]=f2bf(a.z); lo[3]=f2bf(a.w);
    lo[4]=f2bf(b.x); lo[5]=f2bf(b.y); lo[6]=f2bf(b.z); lo[7]=f2bf(b.w);
    hi[0]=f2bf(c.x); hi[1]=f2bf(c.y); hi[2]=f2bf(c.z); hi[3]=f2bf(c.w);
    hi[4]=f2bf(d.x); hi[5]=f2bf(d.y); hi[6]=f2bf(d.z); hi[7]=f2bf(d.w);
    *(bf16x8*)&sX[r * 72 + qq * 16] = lo;
    *(bf16x8*)&sX[r * 72 + qq * 16 + 8] = hi;
  }
  __syncthreads();

  const int lane = tid & 63, w = tid >> 6;
  const int hi4 = lane >> 4, lo16 = lane & 15;
  const int R = w * 16;

  // GEMM1: g = X @ Wgeo
  f32x4 acc[4] = {};
#pragma unroll
  for (int kk = 0; kk < 2; ++kk) {
    const bf16x8 a = *(const bf16x8*)&sX[(R + lo16) * 72 + kk * 32 + hi4 * 8];
#pragma unroll
    for (int n = 0; n < 4; ++n) {
      const bf16x8 b = *(const bf16x8*)&sWg[(n * 16 + lo16) * 72 + kk * 32 + hi4 * 8];
      acc[n] = __builtin_amdgcn_mfma_f32_16x16x32_bf16(a, b, acc[n], 0, 0, 0);
    }
  }
  // LN + ReLU (row = R + hi4*4 + j, col = n*16 + lo16)
  float gam4[4], bet4[4];
#pragma unroll
  for (int n = 0; n < 4; ++n) { gam4[n] = gamma[n * 16 + lo16]; bet4[n] = beta[n * 16 + lo16]; }
#pragma unroll
  for (int j = 0; j < 4; ++j) {
    float s = acc[0][j] + acc[1][j] + acc[2][j] + acc[3][j];
#pragma unroll
    for (int o = 1; o <= 8; o <<= 1) s += __shfl_xor(s, o, 64);
    const float mu = s * (1.f / 64.f);
    float vs = 0.f;
#pragma unroll
    for (int n = 0; n < 4; ++n) { const float d = acc[n][j] - mu; vs = fmaf(d, d, vs); }
#pragma unroll
    for (int o = 1; o <= 8; o <<= 1) vs += __shfl_xor(vs, o, 64);
    const float inv = rsqrtf(vs * (1.f / 64.f) + 1e-5f);
#pragma unroll
    for (int n = 0; n < 4; ++n) {
      const float q = fmaxf(fmaf((acc[n][j] - mu) * inv, gam4[n], bet4[n]), 0.f);
      sQ[(R + hi4 * 4 + j) * 72 + n * 16 + lo16] = f2bf(q);
    }
  }
  __syncthreads();  // make sQ writes (scalar ds_write) visible before vector re-reads
  // GEMM-U: U = q @ Wqk
  f32x4 au[4] = {};
#pragma unroll
  for (int kk = 0; kk < 2; ++kk) {
    const bf16x8 a = *(const bf16x8*)&sQ[(R + lo16) * 72 + kk * 32 + hi4 * 8];
#pragma unroll
    for (int n = 0; n < 4; ++n) {
      const bf16x8 b = *(const bf16x8*)&sWqk[(n * 16 + lo16) * 72 + kk * 32 + hi4 * 8];
      au[n] = __builtin_amdgcn_mfma_f32_16x16x32_bf16(a, b, au[n], 0, 0, 0);
    }
  }
#pragma unroll
  for (int j = 0; j < 4; ++j)
#pragma unroll
    for (int n = 0; n < 4; ++n)
      sX[(R + hi4 * 4 + j) * 72 + n * 16 + lo16] = f2bf(au[n][j]);  // stage U in sX (own rows)
  // GEMM-P: [P | bdy] = q @ Wpos
  f32x4 ap[2] = {};
#pragma unroll
  for (int kk = 0; kk < 2; ++kk) {
    const bf16x8 a = *(const bf16x8*)&sQ[(R + lo16) * 72 + kk * 32 + hi4 * 8];
#pragma unroll
    for (int n = 0; n < 2; ++n) {
      const bf16x8 b = *(const bf16x8*)&sWp[(n * 16 + lo16) * 72 + kk * 32 + hi4 * 8];
      ap[n] = __builtin_amdgcn_mfma_f32_16x16x32_bf16(a, b, ap[n], 0, 0, 0);
    }
  }
  const float bb = bbdy[0];
#pragma unroll
  for (int n = 0; n < 2; ++n) {
    const int col = n * 16 + lo16;
#pragma unroll
    for (int j = 0; j < 4; ++j) {
      const int m = m0 + R + hi4 * 4 + j;
      if (m < M_PTS) {
        if (col < KN) P[(size_t)m * KN + col] = f2bf(ap[n][j]);
        else if (col == KN) out[OFF_BDY + m] = ap[n][j] + bb;
      }
    }
  }
  __syncthreads();
  // coalesced stores of Qg (from sQ) and U (from sX)
  for (int i = tid; i < 512; i += 256) {
    const int r = i >> 3, u = i & 7;
    const int m = m0 + r;
    if (m < M_PTS) {
      *(bf16x8*)&Qg[(size_t)m * 64 + u * 8] = *(const bf16x8*)&sQ[r * 72 + u * 8];
      *(bf16x8*)&U[(size_t)m * 64 + u * 8] = *(const bf16x8*)&sX[r * 72 + u * 8];
    }
  }
  // neighbor / mask outputs
  const bool is64 = nbr_is64(nbrv);
  for (int i = tid; i < 64 * KN; i += 256) {
    const int r = i / KN;
    const int m = m0 + r;
    if (m >= M_PTS) continue;
    const size_t ni = (size_t)m * KN + (i % KN);
    const long long nk = nbr_at(nbrv, is64, ni);
    const int dx = coords[nk * 3 + 0] - coords[m * 3 + 0];
    const int dy = coords[nk * 3 + 1] - coords[m * 3 + 1];
    const int dz = coords[nk * 3 + 2] - coords[m * 3 + 2];
    const int valid = (max(max(abs(dx), abs(dy)), abs(dz)) <= 1) ? 1 : 0;
    out[OFF_NBR + ni] = (float)nk;
    out[OFF_MASK + ni] = (float)valid;
  }
}

// ---------------- k2: gather+softmax+s96 (wave-per-point) then MFMA head ----------------
__global__ __launch_bounds__(256) void k2(const float* __restrict__ sem,
                                          const int* __restrict__ coords,
                                          const void* __restrict__ nbrv,
                                          const float* __restrict__ bout,
                                          const short* __restrict__ ws,
                                          const short* __restrict__ Qg,
                                          const short* __restrict__ U,
                                          const short* __restrict__ P,
                                          float* __restrict__ out) {
  __shared__ short sW1[6656];  // [64][104]
  __shared__ short sW2[1664];  // [16][104]
  __shared__ short sS[6656];   // [64][104] s96 tile
  const int tid = threadIdx.x;
  {
    const bf16x8* a = (const bf16x8*)(ws + WS_W1);
    const bf16x8* b = (const bf16x8*)(ws + WS_W2);
    for (int i = tid; i < 832; i += 256) ((bf16x8*)sW1)[i] = a[i];
    for (int i = tid; i < 208; i += 256) ((bf16x8*)sW2)[i] = b[i];
  }
  const float* b2 = (const float*)(ws + WS_B2);
  const bool is64 = nbr_is64(nbrv);
  __syncthreads();

  const int lane = tid & 63, w = tid >> 6;
  const int hi4 = lane >> 4, lo16 = lane & 15;
  const int R = w * 16;
  const int m0 = blockIdx.x * 64;

  // phase A: wave w handles points m0+R .. m0+R+15
  for (int p = 0; p < 16; ++p) {
    const int lr = R + p;
    const int m = m0 + lr;
    if (m < M_PTS) {
      int nki = 0;
      float logit = -1e30f;
      const int c0 = coords[m * 3 + 0], c1 = coords[m * 3 + 1], c2 = coords[m * 3 + 2];
      if (lane < KN) {
        const long long nk = nbr_at(nbrv, is64, (size_t)m * KN + lane);
        nki = (int)nk;
        const int dx = coords[nk * 3 + 0] - c0;
        const int dy = coords[nk * 3 + 1] - c1;
        const int dz = coords[nk * 3 + 2] - c2;
        if (max(max(abs(dx), abs(dy)), abs(dz)) <= 1) {
          const float pv = bf2f((unsigned short)P[(size_t)m * KN + ((dx + 1) * 9 + (dy + 1) * 3 + (dz + 1))]);
          const bf16x8* qr = (const bf16x8*)(Qg + (size_t)nki * 64);
          const bf16x8* ur = (const bf16x8*)(U + (size_t)m * 64);
          float dot = 0.f;
#pragma unroll
          for (int i = 0; i < 8; ++i) {
            const bf16x8 qa = qr[i];
            const bf16x8 ub = ur[i];
#pragma unroll
            for (int j = 0; j < 8; ++j)
              dot = fmaf(bf2f((unsigned short)qa[j]), bf2f((unsigned short)ub[j]), dot);
          }
          logit = (dot + pv) * 0.125f;
        } else {
          logit = -10000.0f;
        }
      }
      float mx = logit;
#pragma unroll
      for (int o = 16; o >= 1; o >>= 1) mx = fmaxf(mx, __shfl_xor(mx, o, 64));
      const float e = (lane < KN) ? __expf(logit - mx) : 0.f;
      float ss = e;
#pragma unroll
      for (int o = 16; o >= 1; o >>= 1) ss += __shfl_xor(ss, o, 64);
      const float a = e / ss;
      if (lane < KN) out[OFF_AFF + (size_t)m * KN + lane] = a;
      // s96 = sem[m] + sum_k a_k sem[nk]
      float s_lo = sem[(size_t)m * CS + lane];
      float s_hi = (lane < 32) ? sem[(size_t)m * CS + 64 + lane] : 0.f;
      unsigned long long mb = __ballot(lane < KN && a > 0.f);
      while (mb) {
        const int k = __ffsll(mb) - 1;
        mb &= mb - 1;
        const float ak = __shfl(a, k, 64);
        const int nn = __shfl(nki, k, 64);
        s_lo = fmaf(ak, sem[(size_t)nn * CS + lane], s_lo);
        if (lane < 32) s_hi = fmaf(ak, sem[(size_t)nn * CS + 64 + lane], s_hi);
      }
      sS[lr * 104 + lane] = f2bf(s_lo);
      if (lane < 32) sS[lr * 104 + 64 + lane] = f2bf(s_hi);
    } else {
      sS[lr * 104 + lane] = 0;
      if (lane < 32) sS[lr * 104 + 64 + lane] = 0;
    }
  }
  __syncthreads();

  // phase B: rf = S@W1 + bout ; logits = S@W2 + b2
  f32x4 ar[4] = {};
  f32x4 al = {};
#pragma unroll
  for (int kk = 0; kk < 3; ++kk) {
    const bf16x8 a = *(const bf16x8*)&sS[(R + lo16) * 104 + kk * 32 + hi4 * 8];
#pragma unroll
    for (int n = 0; n < 4; ++n) {
      const bf16x8 b = *(const bf16x8*)&sW1[(n * 16 + lo16) * 104 + kk * 32 + hi4 * 8];
      ar[n] = __builtin_amdgcn_mfma_f32_16x16x32_bf16(a, b, ar[n], 0, 0, 0);
    }
    const bf16x8 b = *(const bf16x8*)&sW2[lo16 * 104 + kk * 32 + hi4 * 8];
    al = __builtin_amdgcn_mfma_f32_16x16x32_bf16(a, b, al, 0, 0, 0);
  }
#pragma unroll
  for (int n = 0; n < 4; ++n) {
    const float bo = bout[n * 16 + lo16];
#pragma unroll
    for (int j = 0; j < 4; ++j) {
      const int m = m0 + R + hi4 * 4 + j;
      if (m < M_PTS) out[OFF_RF + (size_t)m * 64 + n * 16 + lo16] = ar[n][j] + bo;
    }
  }
  {
    const float bc = (lo16 < NC) ? b2[lo16] : 0.f;
#pragma unroll
    for (int j = 0; j < 4; ++j) {
      const int m = m0 + R + hi4 * 4 + j;
      if (m < M_PTS && lo16 < NC) out[OFF_LOGITS + (size_t)m * NC + lo16] = al[j] + bc;
    }
  }
}

extern "C" void kernel_launch(void* const* d_in, const int* in_sizes, int n_in,
                              void* d_out, int out_size, void* d_ws, size_t ws_size,
                              hipStream_t stream) {
  const float* geo = (const float*)d_in[0];
  const float* sem = (const float*)d_in[1];
  const int* coords = (const int*)d_in[2];
  const void* nbrv = (const void*)d_in[3];
  const float* Wgeo = (const float*)d_in[4];
  const float* gamma = (const float*)d_in[5];
  const float* beta = (const float*)d_in[6];
  const float* Wbdy = (const float*)d_in[7];
  const float* bbdy = (const float*)d_in[8];
  const float* Wq = (const float*)d_in[9];
  const float* Wk = (const float*)d_in[10];
  const float* Wv = (const float*)d_in[11];
  const float* pos = (const float*)d_in[12];
  const float* Wout = (const float*)d_in[13];
  const float* bout = (const float*)d_in[14];
  const float* Wcls = (const float*)d_in[15];
  const float* bcls = (const float*)d_in[16];

  short* ws = (short*)d_ws;
  short* Qg = ws + WS_QG;
  short* U = ws + WS_U;
  short* P = ws + WS_P;
  float* out = (float*)d_out;

  const int blocks = (M_PTS + 63) / 64;  // 1563
  k0<<<1, 1024, 0, stream>>>(Wgeo, Wbdy, Wq, Wk, Wv, pos, Wout, bout, Wcls, bcls, ws);
  k1<<<blocks, 256, 0, stream>>>(geo, coords, nbrv, gamma, beta, bbdy, ws, Qg, U, P, out);
  k2<<<blocks, 256, 0, stream>>>(sem, coords, nbrv, bout, ws, Qg, U, P, out);
}

// Round 7
// 258.954 us; speedup vs baseline: 5.4705x; 1.7259x over previous
//
#include <hip/hip_runtime.h>
#include <hip/hip_bf16.h>

#define M_PTS 100000
#define KN 27
#define CS 96
#define NC 13

// flat output offsets (f32 elements), return order:
// logits[M,13], bdy[M,1], affinity[M,1,27], refined[M,64], neighbor[M,27], mask[M,27]
#define OFF_LOGITS 0ull
#define OFF_BDY    1300000ull
#define OFF_AFF    1400000ull
#define OFF_RF     4100000ull
#define OFF_NBR    10500000ull
#define OFF_MASK   13200000ull

// ws layout (units = shorts/bf16)
#define WS_QG   0ull                    // [M][64] bf16
#define WS_U    6400000ull              // [M][64] bf16
#define WS_P    12800000ull             // [M][27] bf16
#define WS_WGEO 15500000ull             // [64][72]  WgeoB[d][c] = Wgeo[c][d]
#define WS_WQK  (WS_WGEO + 4608ull)     // [64][72]  WqkB[d][c]  = sum_t Wq[c][t]Wk[d][t]
#define WS_WPOS (WS_WQK + 4608ull)      // [32][72]  rows 0-26: sum_t Wq[c][t]pos[j][t]; row 27: Wbdy
#define WS_W1   (WS_WPOS + 2304ull)     // [64][104] W1B[d][s] = sum_t Wv[s][t]Wout[t][d]
#define WS_W2   (WS_W1 + 6656ull)       // [16][104] W2B[j][s] = sum_t Wv[s][t]V[t][j]
#define WS_B2   (WS_W2 + 1664ull)       // f32[16]: b2[j] = bout@Wcls[:,j] + bcls[j]

typedef float f4 __attribute__((ext_vector_type(4)));
typedef float f32x4 __attribute__((ext_vector_type(4)));
typedef short bf16x8 __attribute__((ext_vector_type(8)));

__device__ __forceinline__ short f2bf(float f) {
  union { float f; unsigned int u; } x; x.f = f;
  unsigned int r = x.u + 0x7fffu + ((x.u >> 16) & 1u);
  return (short)(r >> 16);
}
__device__ __forceinline__ float bf2f(unsigned short u) {
  union { unsigned int i; float f; } x; x.i = ((unsigned int)u) << 16;
  return x.f;
}
__device__ __forceinline__ bool nbr_is64(const void* nbrv) {
  const int* w = (const int*)nbrv;
  bool is64 = true;
#pragma unroll
  for (int j = 1; j < 64; j += 2) is64 = is64 && (w[j] == 0);
  return is64;
}
__device__ __forceinline__ long long nbr_at(const void* nbrv, bool is64, size_t i) {
  return is64 ? ((const long long*)nbrv)[i] : (long long)((const int*)nbrv)[i];
}

// ---------------- k0: fused weights, task-parallel over 32 blocks ----------------
__global__ __launch_bounds__(256) void k0(const float* __restrict__ Wgeo,
                                          const float* __restrict__ Wbdy,
                                          const float* __restrict__ Wq,
                                          const float* __restrict__ Wk,
                                          const float* __restrict__ Wv,
                                          const float* __restrict__ pos,
                                          const float* __restrict__ Wout,
                                          short* __restrict__ ws) {
  const int gid = blockIdx.x * 256 + threadIdx.x;
  const int NT = gridDim.x * 256;
  for (int i = gid; i < 16384; i += NT) {
    if (i < 4096) {
      const int d = i >> 6, c = i & 63;
      ws[WS_WGEO + d * 72 + c] = f2bf(Wgeo[c * 64 + d]);
    } else if (i < 8192) {
      const int t = i - 4096, d = t >> 6, c = t & 63;
      float s = 0.f;
#pragma unroll 8
      for (int q = 0; q < 64; ++q) s = fmaf(Wq[c * 64 + q], Wk[d * 64 + q], s);
      ws[WS_WQK + d * 72 + c] = f2bf(s);
    } else if (i < 10240) {
      const int t = i - 8192, j = t >> 6, c = t & 63;
      float s = 0.f;
      if (j < 27) {
#pragma unroll 8
        for (int q = 0; q < 64; ++q) s = fmaf(Wq[c * 64 + q], pos[j * 64 + q], s);
      } else if (j == 27) {
        s = Wbdy[c];
      }
      ws[WS_WPOS + j * 72 + c] = f2bf(s);
    } else {
      const int t = i - 10240, d = t / 96, sc = t % 96;
      float a = 0.f;
#pragma unroll 8
      for (int q = 0; q < 64; ++q) a = fmaf(Wv[sc * 64 + q], Wout[q * 64 + d], a);
      ws[WS_W1 + d * 104 + sc] = f2bf(a);
    }
  }
}

// ---------------- k0b: V = Wout@Wcls (LDS), W2, b2 (1 tiny block) ----------------
__global__ __launch_bounds__(256) void k0b(const float* __restrict__ Wv,
                                           const float* __restrict__ Wout,
                                           const float* __restrict__ bout,
                                           const float* __restrict__ Wcls,
                                           const float* __restrict__ bcls,
                                           short* __restrict__ ws) {
  __shared__ float V[64 * NC];
  const int tid = threadIdx.x;
  for (int i = tid; i < 64 * NC; i += 256) {
    const int t = i / NC, j = i % NC;
    float a = 0.f;
#pragma unroll 8
    for (int d = 0; d < 64; ++d) a = fmaf(Wout[t * 64 + d], Wcls[d * NC + j], a);
    V[i] = a;
  }
  __syncthreads();
  for (int i = tid; i < 16 * 96; i += 256) {
    const int j = i / 96, s = i % 96;
    float a = 0.f;
    if (j < NC) {
#pragma unroll 8
      for (int t = 0; t < 64; ++t) a = fmaf(Wv[s * 64 + t], V[t * NC + j], a);
    }
    ws[WS_W2 + j * 104 + s] = f2bf(a);
  }
  float* b2 = (float*)(ws + WS_B2);
  for (int i = tid; i < 16; i += 256) {
    float a = 0.f;
    if (i < NC) {
      for (int d = 0; d < 64; ++d) a = fmaf(bout[d], Wcls[d * NC + i], a);
      a += bcls[i];
    }
    b2[i] = a;
  }
}

// ---------------- k1: 64-pt tile MFMA: geo@Wgeo -> LN/ReLU -> q; U=q@Wqk; [P|bdy]=q@Wpos ----------------
__global__ __launch_bounds__(256) void k1(const float* __restrict__ geo,
                                          const int* __restrict__ coords,
                                          const void* __restrict__ nbrv,
                                          const float* __restrict__ gamma,
                                          const float* __restrict__ beta,
                                          const float* __restrict__ bbdy,
                                          const short* __restrict__ ws,
                                          short* __restrict__ Qg,
                                          short* __restrict__ U,
                                          short* __restrict__ P,
                                          float* __restrict__ out) {
  __shared__ short sX[4608];   // [64][72]  X-tile then U staging
  __shared__ short sQ[4608];   // [64][72]  q tile
  __shared__ short sWg[4608];
  __shared__ short sWqk[4608];
  __shared__ short sWp[2304];
  const int tid = threadIdx.x;
  {
    const bf16x8* a = (const bf16x8*)(ws + WS_WGEO);
    const bf16x8* b = (const bf16x8*)(ws + WS_WQK);
    const bf16x8* c = (const bf16x8*)(ws + WS_WPOS);
    for (int i = tid; i < 576; i += 256) ((bf16x8*)sWg)[i] = a[i];
    for (int i = tid; i < 576; i += 256) ((bf16x8*)sWqk)[i] = b[i];
    for (int i = tid; i < 288; i += 256) ((bf16x8*)sWp)[i] = c[i];
  }
  const int m0 = blockIdx.x * 64;
  {
    const int r = tid >> 2, qq = tid & 3;
    const int m = min(m0 + r, M_PTS - 1);
    const f4* g = (const f4*)(geo + (size_t)m * 64 + qq * 16);
    const f4 a = g[0], b = g[1], c = g[2], d = g[3];
    bf16x8 lo, hi;
    lo[0]=f2bf(a.x); lo[1]=f2bf(a.y); lo[2]=f2bf(a.z); lo[3]=f2bf(a.w);
    lo[4]=f2bf(b.x); lo[5]=f2bf(b.y); lo[6]=f2bf(b.z); lo[7]=f2bf(b.w);
    hi[0]=f2bf(c.x); hi[1]=f2bf(c.y); hi[2]=f2bf(c.z); hi[3]=f2bf(c.w);
    hi[4]=f2bf(d.x); hi[5]=f2bf(d.y); hi[6]=f2bf(d.z); hi[7]=f2bf(d.w);
    *(bf16x8*)&sX[r * 72 + qq * 16] = lo;
    *(bf16x8*)&sX[r * 72 + qq * 16 + 8] = hi;
  }
  __syncthreads();

  const int lane = tid & 63, w = tid >> 6;
  const int hi4 = lane >> 4, lo16 = lane & 15;
  const int R = w * 16;

  // GEMM1: g = X @ Wgeo
  f32x4 acc[4] = {};
#pragma unroll
  for (int kk = 0; kk < 2; ++kk) {
    const bf16x8 a = *(const bf16x8*)&sX[(R + lo16) * 72 + kk * 32 + hi4 * 8];
#pragma unroll
    for (int n = 0; n < 4; ++n) {
      const bf16x8 b = *(const bf16x8*)&sWg[(n * 16 + lo16) * 72 + kk * 32 + hi4 * 8];
      acc[n] = __builtin_amdgcn_mfma_f32_16x16x32_bf16(a, b, acc[n], 0, 0, 0);
    }
  }
  // LN + ReLU
  float gam4[4], bet4[4];
#pragma unroll
  for (int n = 0; n < 4; ++n) { gam4[n] = gamma[n * 16 + lo16]; bet4[n] = beta[n * 16 + lo16]; }
#pragma unroll
  for (int j = 0; j < 4; ++j) {
    float s = acc[0][j] + acc[1][j] + acc[2][j] + acc[3][j];
#pragma unroll
    for (int o = 1; o <= 8; o <<= 1) s += __shfl_xor(s, o, 64);
    const float mu = s * (1.f / 64.f);
    float vs = 0.f;
#pragma unroll
    for (int n = 0; n < 4; ++n) { const float d = acc[n][j] - mu; vs = fmaf(d, d, vs); }
#pragma unroll
    for (int o = 1; o <= 8; o <<= 1) vs += __shfl_xor(vs, o, 64);
    const float inv = rsqrtf(vs * (1.f / 64.f) + 1e-5f);
#pragma unroll
    for (int n = 0; n < 4; ++n) {
      const float q = fmaxf(fmaf((acc[n][j] - mu) * inv, gam4[n], bet4[n]), 0.f);
      sQ[(R + hi4 * 4 + j) * 72 + n * 16 + lo16] = f2bf(q);
    }
  }
  __syncthreads();
  // GEMM-U: U = q @ Wqk
  f32x4 au[4] = {};
#pragma unroll
  for (int kk = 0; kk < 2; ++kk) {
    const bf16x8 a = *(const bf16x8*)&sQ[(R + lo16) * 72 + kk * 32 + hi4 * 8];
#pragma unroll
    for (int n = 0; n < 4; ++n) {
      const bf16x8 b = *(const bf16x8*)&sWqk[(n * 16 + lo16) * 72 + kk * 32 + hi4 * 8];
      au[n] = __builtin_amdgcn_mfma_f32_16x16x32_bf16(a, b, au[n], 0, 0, 0);
    }
  }
#pragma unroll
  for (int j = 0; j < 4; ++j)
#pragma unroll
    for (int n = 0; n < 4; ++n)
      sX[(R + hi4 * 4 + j) * 72 + n * 16 + lo16] = f2bf(au[n][j]);
  // GEMM-P: [P | bdy] = q @ Wpos
  f32x4 ap[2] = {};
#pragma unroll
  for (int kk = 0; kk < 2; ++kk) {
    const bf16x8 a = *(const bf16x8*)&sQ[(R + lo16) * 72 + kk * 32 + hi4 * 8];
#pragma unroll
    for (int n = 0; n < 2; ++n) {
      const bf16x8 b = *(const bf16x8*)&sWp[(n * 16 + lo16) * 72 + kk * 32 + hi4 * 8];
      ap[n] = __builtin_amdgcn_mfma_f32_16x16x32_bf16(a, b, ap[n], 0, 0, 0);
    }
  }
  const float bb = bbdy[0];
#pragma unroll
  for (int n = 0; n < 2; ++n) {
    const int col = n * 16 + lo16;
#pragma unroll
    for (int j = 0; j < 4; ++j) {
      const int m = m0 + R + hi4 * 4 + j;
      if (m < M_PTS) {
        if (col < KN) P[(size_t)m * KN + col] = f2bf(ap[n][j]);
        else if (col == KN) out[OFF_BDY + m] = ap[n][j] + bb;
      }
    }
  }
  __syncthreads();
  for (int i = tid; i < 512; i += 256) {
    const int r = i >> 3, u = i & 7;
    const int m = m0 + r;
    if (m < M_PTS) {
      *(bf16x8*)&Qg[(size_t)m * 64 + u * 8] = *(const bf16x8*)&sQ[r * 72 + u * 8];
      *(bf16x8*)&U[(size_t)m * 64 + u * 8] = *(const bf16x8*)&sX[r * 72 + u * 8];
    }
  }
  // neighbor / mask: constant-trip unroll so loads batch across bodies
  const bool is64 = nbr_is64(nbrv);
#pragma unroll
  for (int it = 0; it < 7; ++it) {
    const int i = it * 256 + tid;
    if (it < 6 || i < 64 * KN) {
      const int r = i / KN, kq = i - r * KN;
      const int m = m0 + r;
      if (m < M_PTS) {
        const size_t ni = (size_t)m * KN + kq;
        const long long nk = nbr_at(nbrv, is64, ni);
        const int dx = coords[nk * 3 + 0] - coords[m * 3 + 0];
        const int dy = coords[nk * 3 + 1] - coords[m * 3 + 1];
        const int dz = coords[nk * 3 + 2] - coords[m * 3 + 2];
        const int valid = (max(max(abs(dx), abs(dy)), abs(dz)) <= 1) ? 1 : 0;
        out[OFF_NBR + ni] = (float)nk;
        out[OFF_MASK + ni] = (float)valid;
      }
    }
  }
}

// ---------------- k2: batched gather+softmax+s96 (4-pt batches), then MFMA head ----------------
__global__ __launch_bounds__(256) void k2(const float* __restrict__ sem,
                                          const int* __restrict__ coords,
                                          const void* __restrict__ nbrv,
                                          const float* __restrict__ bout,
                                          const short* __restrict__ ws,
                                          const short* __restrict__ Qg,
                                          const short* __restrict__ U,
                                          const short* __restrict__ P,
                                          float* __restrict__ out) {
  __shared__ short sW1[6656];  // [64][104]
  __shared__ short sW2[1664];  // [16][104]
  __shared__ short sS[6656];   // [64][104] s96 tile
  const int tid = threadIdx.x;
  {
    const bf16x8* a = (const bf16x8*)(ws + WS_W1);
    const bf16x8* b = (const bf16x8*)(ws + WS_W2);
    for (int i = tid; i < 832; i += 256) ((bf16x8*)sW1)[i] = a[i];
    for (int i = tid; i < 208; i += 256) ((bf16x8*)sW2)[i] = b[i];
  }
  const float* b2 = (const float*)(ws + WS_B2);
  const bool is64 = nbr_is64(nbrv);
  __syncthreads();

  const int lane = tid & 63, w = tid >> 6;
  const int hi4 = lane >> 4, lo16 = lane & 15;
  const int R = w * 16;
  const int m0 = blockIdx.x * 64;
  const int pbase = m0 + R;
  const int kl = (lane < KN) ? lane : KN - 1;
  const int l31 = lane & 31;

  // phase A: 16 points in 4 batches of 4 (interleaved latency chains)
  for (int batch = 0; batch < 4; ++batch) {
    int mm[4], msafe[4], nk[4], vflag[4], pidx[4];
#pragma unroll
    for (int b = 0; b < 4; ++b) {
      mm[b] = pbase + batch * 4 + b;
      msafe[b] = min(mm[b], M_PTS - 1);
      nk[b] = (int)nbr_at(nbrv, is64, (size_t)msafe[b] * KN + kl);
    }
#pragma unroll
    for (int b = 0; b < 4; ++b) {
      const int c0 = coords[msafe[b] * 3 + 0];
      const int c1 = coords[msafe[b] * 3 + 1];
      const int c2 = coords[msafe[b] * 3 + 2];
      const int dx = coords[nk[b] * 3 + 0] - c0;
      const int dy = coords[nk[b] * 3 + 1] - c1;
      const int dz = coords[nk[b] * 3 + 2] - c2;
      vflag[b] = (lane < KN) && (max(max(abs(dx), abs(dy)), abs(dz)) <= 1);
      pidx[b] = vflag[b] ? ((dx + 1) * 9 + (dy + 1) * 3 + (dz + 1)) : 13;
    }
    float uv[4], qs[4], pval[4];
#pragma unroll
    for (int b = 0; b < 4; ++b) {
      uv[b] = bf2f((unsigned short)U[(size_t)msafe[b] * 64 + lane]);
      qs[b] = bf2f((unsigned short)Qg[(size_t)msafe[b] * 64 + lane]);
      pval[b] = bf2f((unsigned short)P[(size_t)msafe[b] * KN + pidx[b]]);
    }
    // self-neighbor dot (lane 0 is guaranteed self): 4 interleaved butterflies
    float ds[4];
#pragma unroll
    for (int b = 0; b < 4; ++b) ds[b] = qs[b] * uv[b];
#pragma unroll
    for (int o = 1; o < 64; o <<= 1)
#pragma unroll
      for (int b = 0; b < 4; ++b) ds[b] += __shfl_xor(ds[b], o, 64);
    float lg[4];
#pragma unroll
    for (int b = 0; b < 4; ++b)
      lg[b] = (lane == 0) ? (ds[b] + pval[b]) * 0.125f : -10000.f;
    // rare extra valid neighbors (wave-uniform branch, ~0.3% of points)
#pragma unroll
    for (int b = 0; b < 4; ++b) {
      unsigned long long eb = __ballot(vflag[b] != 0) & ~1ull;
      while (eb) {
        const int k = __ffsll(eb) - 1; eb &= eb - 1;
        const int nn = __shfl(nk[b], k, 64);
        float dd = bf2f((unsigned short)Qg[(size_t)nn * 64 + lane]) * uv[b];
#pragma unroll
        for (int o = 1; o < 64; o <<= 1) dd += __shfl_xor(dd, o, 64);
        const float pv = __shfl(pval[b], k, 64);
        if (lane == k) lg[b] = (dd + pv) * 0.125f;
      }
    }
    // softmax over lanes 0..26 (5-level, interleaved)
    float mx[4], ee[4], ssum[4], aa[4];
#pragma unroll
    for (int b = 0; b < 4; ++b) mx[b] = lg[b];
#pragma unroll
    for (int o = 1; o < 32; o <<= 1)
#pragma unroll
      for (int b = 0; b < 4; ++b) mx[b] = fmaxf(mx[b], __shfl_xor(mx[b], o, 64));
#pragma unroll
    for (int b = 0; b < 4; ++b) ee[b] = (lane < KN) ? __expf(lg[b] - mx[b]) : 0.f;
#pragma unroll
    for (int b = 0; b < 4; ++b) ssum[b] = ee[b];
#pragma unroll
    for (int o = 1; o < 32; o <<= 1)
#pragma unroll
      for (int b = 0; b < 4; ++b) ssum[b] += __shfl_xor(ssum[b], o, 64);
#pragma unroll
    for (int b = 0; b < 4; ++b) aa[b] = ee[b] / ssum[b];
#pragma unroll
    for (int b = 0; b < 4; ++b)
      if (mm[b] < M_PTS && lane < KN) out[OFF_AFF + (size_t)mm[b] * KN + lane] = aa[b];
    // s96 = (1 + a_self)*sem[m] + sum_extra a_k*sem[nk]
    float a0[4], slo[4], shi[4];
#pragma unroll
    for (int b = 0; b < 4; ++b) a0[b] = __shfl(aa[b], 0, 64);
#pragma unroll
    for (int b = 0; b < 4; ++b) {
      slo[b] = sem[(size_t)msafe[b] * CS + lane] * (1.f + a0[b]);
      shi[b] = sem[(size_t)msafe[b] * CS + 64 + l31] * (1.f + a0[b]);
    }
#pragma unroll
    for (int b = 0; b < 4; ++b) {
      unsigned long long mb2 = __ballot(aa[b] > 0.f && lane > 0 && lane < KN);
      while (mb2) {
        const int k = __ffsll(mb2) - 1; mb2 &= mb2 - 1;
        const float ak = __shfl(aa[b], k, 64);
        const int nn = __shfl(nk[b], k, 64);
        slo[b] = fmaf(ak, sem[(size_t)nn * CS + lane], slo[b]);
        shi[b] = fmaf(ak, sem[(size_t)nn * CS + 64 + l31], shi[b]);
      }
    }
#pragma unroll
    for (int b = 0; b < 4; ++b) {
      const int lr = R + batch * 4 + b;
      sS[lr * 104 + lane] = f2bf(slo[b]);
      if (lane < 32) sS[lr * 104 + 64 + lane] = f2bf(shi[b]);
    }
  }
  __syncthreads();

  // phase B: rf = S@W1 + bout ; logits = S@W2 + b2
  f32x4 ar[4] = {};
  f32x4 al = {};
#pragma unroll
  for (int kk = 0; kk < 3; ++kk) {
    const bf16x8 a = *(const bf16x8*)&sS[(R + lo16) * 104 + kk * 32 + hi4 * 8];
#pragma unroll
    for (int n = 0; n < 4; ++n) {
      const bf16x8 b = *(const bf16x8*)&sW1[(n * 16 + lo16) * 104 + kk * 32 + hi4 * 8];
      ar[n] = __builtin_amdgcn_mfma_f32_16x16x32_bf16(a, b, ar[n], 0, 0, 0);
    }
    const bf16x8 b = *(const bf16x8*)&sW2[lo16 * 104 + kk * 32 + hi4 * 8];
    al = __builtin_amdgcn_mfma_f32_16x16x32_bf16(a, b, al, 0, 0, 0);
  }
#pragma unroll
  for (int n = 0; n < 4; ++n) {
    const float bo = bout[n * 16 + lo16];
#pragma unroll
    for (int j = 0; j < 4; ++j) {
      const int m = m0 + R + hi4 * 4 + j;
      if (m < M_PTS) out[OFF_RF + (size_t)m * 64 + n * 16 + lo16] = ar[n][j] + bo;
    }
  }
  {
    const float bc = (lo16 < NC) ? b2[lo16] : 0.f;
#pragma unroll
    for (int j = 0; j < 4; ++j) {
      const int m = m0 + R + hi4 * 4 + j;
      if (m < M_PTS && lo16 < NC) out[OFF_LOGITS + (size_t)m * NC + lo16] = al[j] + bc;
    }
  }
}

extern "C" void kernel_launch(void* const* d_in, const int* in_sizes, int n_in,
                              void* d_out, int out_size, void* d_ws, size_t ws_size,
                              hipStream_t stream) {
  const float* geo = (const float*)d_in[0];
  const float* sem = (const float*)d_in[1];
  const int* coords = (const int*)d_in[2];
  const void* nbrv = (const void*)d_in[3];
  const float* Wgeo = (const float*)d_in[4];
  const float* gamma = (const float*)d_in[5];
  const float* beta = (const float*)d_in[6];
  const float* Wbdy = (const float*)d_in[7];
  const float* bbdy = (const float*)d_in[8];
  const float* Wq = (const float*)d_in[9];
  const float* Wk = (const float*)d_in[10];
  const float* Wv = (const float*)d_in[11];
  const float* pos = (const float*)d_in[12];
  const float* Wout = (const float*)d_in[13];
  const float* bout = (const float*)d_in[14];
  const float* Wcls = (const float*)d_in[15];
  const float* bcls = (const float*)d_in[16];

  short* ws = (short*)d_ws;
  short* Qg = ws + WS_QG;
  short* U = ws + WS_U;
  short* P = ws + WS_P;
  float* out = (float*)d_out;

  const int blocks = (M_PTS + 63) / 64;  // 1563
  k0<<<32, 256, 0, stream>>>(Wgeo, Wbdy, Wq, Wk, Wv, pos, Wout, ws);
  k0b<<<1, 256, 0, stream>>>(Wv, Wout, bout, Wcls, bcls, ws);
  k1<<<blocks, 256, 0, stream>>>(geo, coords, nbrv, gamma, beta, bbdy, ws, Qg, U, P, out);
  k2<<<blocks, 256, 0, stream>>>(sem, coords, nbrv, bout, ws, Qg, U, P, out);
}

// Round 8
// 222.745 us; speedup vs baseline: 6.3598x; 1.1626x over previous
//
#include <hip/hip_runtime.h>
#include <hip/hip_bf16.h>

#define M_PTS 100000
#define KN 27
#define CS 96
#define NC 13

// flat output offsets (f32 elements), return order:
// logits[M,13], bdy[M,1], affinity[M,1,27], refined[M,64], neighbor[M,27], mask[M,27]
#define OFF_LOGITS 0ull
#define OFF_BDY    1300000ull
#define OFF_AFF    1400000ull
#define OFF_RF     4100000ull
#define OFF_NBR    10500000ull
#define OFF_MASK   13200000ull

// ws layout (units = shorts/bf16)
#define WS_QG   0ull                    // [M][64] bf16
#define WS_U    6400000ull              // [M][64] bf16
#define WS_P    12800000ull             // [M][27] bf16
#define WS_WGEO 15500000ull             // [64][72]  WgeoB[d][c] = Wgeo[c][d]
#define WS_WQK  (WS_WGEO + 4608ull)     // [64][72]  WqkB[d][c]  = sum_t Wq[c][t]Wk[d][t]
#define WS_WPOS (WS_WQK + 4608ull)      // [32][72]  rows 0-26: sum_t Wq[c][t]pos[j][t]; row 27: Wbdy
#define WS_W1   (WS_WPOS + 2304ull)     // [64][104] W1B[d][s] = sum_t Wv[s][t]Wout[t][d]
#define WS_W2   (WS_W1 + 6656ull)       // [16][104] W2B[j][s] = sum_t Wv[s][t]V[t][j]
#define WS_B2   (WS_W2 + 1664ull)       // f32[16]: b2[j] = bout@Wcls[:,j] + bcls[j]
#define WS_VM   (WS_B2 + 32ull)         // u32[M]: per-point valid-lane bitmask

typedef float f4 __attribute__((ext_vector_type(4)));
typedef float f32x4 __attribute__((ext_vector_type(4)));
typedef short bf16x8 __attribute__((ext_vector_type(8)));
typedef short s16x4 __attribute__((ext_vector_type(4)));

__device__ __forceinline__ short f2bf(float f) {
  union { float f; unsigned int u; } x; x.f = f;
  unsigned int r = x.u + 0x7fffu + ((x.u >> 16) & 1u);
  return (short)(r >> 16);
}
__device__ __forceinline__ float bf2f(unsigned short u) {
  union { unsigned int i; float f; } x; x.i = ((unsigned int)u) << 16;
  return x.f;
}
__device__ __forceinline__ bool nbr_is64(const void* nbrv) {
  const int* w = (const int*)nbrv;
  bool is64 = true;
#pragma unroll
  for (int j = 1; j < 64; j += 2) is64 = is64 && (w[j] == 0);
  return is64;
}
__device__ __forceinline__ long long nbr_at(const void* nbrv, bool is64, size_t i) {
  return is64 ? ((const long long*)nbrv)[i] : (long long)((const int*)nbrv)[i];
}

// ---------------- k0: all fused weights, 38 blocks (0-31: main; 32-37: W2/b2) ----------------
__global__ __launch_bounds__(256) void k0(const float* __restrict__ Wgeo,
                                          const float* __restrict__ Wbdy,
                                          const float* __restrict__ Wq,
                                          const float* __restrict__ Wk,
                                          const float* __restrict__ Wv,
                                          const float* __restrict__ pos,
                                          const float* __restrict__ Wout,
                                          const float* __restrict__ bout,
                                          const float* __restrict__ Wcls,
                                          const float* __restrict__ bcls,
                                          short* __restrict__ ws) {
  __shared__ float V[64 * NC];
  const int tid = threadIdx.x, blk = blockIdx.x;
  if (blk < 32) {
    for (int i = blk * 256 + tid; i < 16384; i += 8192) {
      if (i < 4096) {
        const int d = i >> 6, c = i & 63;
        ws[WS_WGEO + d * 72 + c] = f2bf(Wgeo[c * 64 + d]);
      } else if (i < 8192) {
        const int t = i - 4096, d = t >> 6, c = t & 63;
        float s = 0.f;
#pragma unroll 8
        for (int q = 0; q < 64; ++q) s = fmaf(Wq[c * 64 + q], Wk[d * 64 + q], s);
        ws[WS_WQK + d * 72 + c] = f2bf(s);
      } else if (i < 10240) {
        const int t = i - 8192, j = t >> 6, c = t & 63;
        float s = 0.f;
        if (j < 27) {
#pragma unroll 8
          for (int q = 0; q < 64; ++q) s = fmaf(Wq[c * 64 + q], pos[j * 64 + q], s);
        } else if (j == 27) {
          s = Wbdy[c];
        }
        ws[WS_WPOS + j * 72 + c] = f2bf(s);
      } else {
        const int t = i - 10240, d = t / 96, sc = t % 96;
        float a = 0.f;
#pragma unroll 8
        for (int q = 0; q < 64; ++q) a = fmaf(Wv[sc * 64 + q], Wout[q * 64 + d], a);
        ws[WS_W1 + d * 104 + sc] = f2bf(a);
      }
    }
  } else {
    // V = Wout @ Wcls (per-block LDS copy), then a slice of W2 = Wv @ V
    for (int i = tid; i < 64 * NC; i += 256) {
      const int t = i / NC, j = i % NC;
      float a = 0.f;
#pragma unroll 8
      for (int d = 0; d < 64; ++d) a = fmaf(Wout[t * 64 + d], Wcls[d * NC + j], a);
      V[i] = a;
    }
    __syncthreads();
    const int g = (blk - 32) * 256 + tid;
    if (g < 16 * 96) {
      const int j = g / 96, s = g % 96;
      float a = 0.f;
      if (j < NC) {
#pragma unroll 8
        for (int t = 0; t < 64; ++t) a = fmaf(Wv[s * 64 + t], V[t * NC + j], a);
      }
      ws[WS_W2 + j * 104 + s] = f2bf(a);
    }
    if (blk == 32 && tid < 16) {
      float a = 0.f;
      if (tid < NC) {
        for (int d = 0; d < 64; ++d) a = fmaf(bout[d], Wcls[d * NC + tid], a);
        a += bcls[tid];
      }
      ((float*)(ws + WS_B2))[tid] = a;
    }
  }
}

// ---------------- k1: 64-pt tile MFMA + LN/ReLU + U/P + nbr/mask/vmask ----------------
__global__ __launch_bounds__(256) void k1(const float* __restrict__ geo,
                                          const int* __restrict__ coords,
                                          const void* __restrict__ nbrv,
                                          const float* __restrict__ gamma,
                                          const float* __restrict__ beta,
                                          const float* __restrict__ bbdy,
                                          const short* __restrict__ ws,
                                          short* __restrict__ Qg,
                                          short* __restrict__ U,
                                          short* __restrict__ P,
                                          unsigned int* __restrict__ vmask,
                                          float* __restrict__ out) {
  __shared__ short sX[4608];   // [64][72]  X-tile then U staging
  __shared__ short sQ[4608];   // [64][72]  q tile
  __shared__ short sWg[4608];
  __shared__ short sWqk[4608];
  __shared__ short sWp[2304];
  const int tid = threadIdx.x;
  {
    const bf16x8* a = (const bf16x8*)(ws + WS_WGEO);
    const bf16x8* b = (const bf16x8*)(ws + WS_WQK);
    const bf16x8* c = (const bf16x8*)(ws + WS_WPOS);
    for (int i = tid; i < 576; i += 256) ((bf16x8*)sWg)[i] = a[i];
    for (int i = tid; i < 576; i += 256) ((bf16x8*)sWqk)[i] = b[i];
    for (int i = tid; i < 288; i += 256) ((bf16x8*)sWp)[i] = c[i];
  }
  const int m0 = blockIdx.x * 64;
  {
    const int r = tid >> 2, qq = tid & 3;
    const int m = min(m0 + r, M_PTS - 1);
    const f4* g = (const f4*)(geo + (size_t)m * 64 + qq * 16);
    const f4 a = g[0], b = g[1], c = g[2], d = g[3];
    bf16x8 lo, hi;
    lo[0]=f2bf(a.x); lo[1]=f2bf(a.y); lo[2]=f2bf(a.z); lo[3]=f2bf(a.w);
    lo[4]=f2bf(b.x); lo[5]=f2bf(b.y); lo[6]=f2bf(b.z); lo[7]=f2bf(b.w);
    hi[0]=f2bf(c.x); hi[1]=f2bf(c.y); hi[2]=f2bf(c.z); hi[3]=f2bf(c.w);
    hi[4]=f2bf(d.x); hi[5]=f2bf(d.y); hi[6]=f2bf(d.z); hi[7]=f2bf(d.w);
    *(bf16x8*)&sX[r * 72 + qq * 16] = lo;
    *(bf16x8*)&sX[r * 72 + qq * 16 + 8] = hi;
  }
  __syncthreads();

  const int lane = tid & 63, w = tid >> 6;
  const int hi4 = lane >> 4, lo16 = lane & 15;
  const int R = w * 16;

  // GEMM1: g = X @ Wgeo
  f32x4 acc[4] = {};
#pragma unroll
  for (int kk = 0; kk < 2; ++kk) {
    const bf16x8 a = *(const bf16x8*)&sX[(R + lo16) * 72 + kk * 32 + hi4 * 8];
#pragma unroll
    for (int n = 0; n < 4; ++n) {
      const bf16x8 b = *(const bf16x8*)&sWg[(n * 16 + lo16) * 72 + kk * 32 + hi4 * 8];
      acc[n] = __builtin_amdgcn_mfma_f32_16x16x32_bf16(a, b, acc[n], 0, 0, 0);
    }
  }
  // LN + ReLU
  float gam4[4], bet4[4];
#pragma unroll
  for (int n = 0; n < 4; ++n) { gam4[n] = gamma[n * 16 + lo16]; bet4[n] = beta[n * 16 + lo16]; }
#pragma unroll
  for (int j = 0; j < 4; ++j) {
    float s = acc[0][j] + acc[1][j] + acc[2][j] + acc[3][j];
#pragma unroll
    for (int o = 1; o <= 8; o <<= 1) s += __shfl_xor(s, o, 64);
    const float mu = s * (1.f / 64.f);
    float vs = 0.f;
#pragma unroll
    for (int n = 0; n < 4; ++n) { const float d = acc[n][j] - mu; vs = fmaf(d, d, vs); }
#pragma unroll
    for (int o = 1; o <= 8; o <<= 1) vs += __shfl_xor(vs, o, 64);
    const float inv = rsqrtf(vs * (1.f / 64.f) + 1e-5f);
#pragma unroll
    for (int n = 0; n < 4; ++n) {
      const float q = fmaxf(fmaf((acc[n][j] - mu) * inv, gam4[n], bet4[n]), 0.f);
      sQ[(R + hi4 * 4 + j) * 72 + n * 16 + lo16] = f2bf(q);
    }
  }
  __syncthreads();
  // GEMM-U: U = q @ Wqk
  f32x4 au[4] = {};
#pragma unroll
  for (int kk = 0; kk < 2; ++kk) {
    const bf16x8 a = *(const bf16x8*)&sQ[(R + lo16) * 72 + kk * 32 + hi4 * 8];
#pragma unroll
    for (int n = 0; n < 4; ++n) {
      const bf16x8 b = *(const bf16x8*)&sWqk[(n * 16 + lo16) * 72 + kk * 32 + hi4 * 8];
      au[n] = __builtin_amdgcn_mfma_f32_16x16x32_bf16(a, b, au[n], 0, 0, 0);
    }
  }
#pragma unroll
  for (int j = 0; j < 4; ++j)
#pragma unroll
    for (int n = 0; n < 4; ++n)
      sX[(R + hi4 * 4 + j) * 72 + n * 16 + lo16] = f2bf(au[n][j]);
  // GEMM-P: [P | bdy] = q @ Wpos
  f32x4 ap[2] = {};
#pragma unroll
  for (int kk = 0; kk < 2; ++kk) {
    const bf16x8 a = *(const bf16x8*)&sQ[(R + lo16) * 72 + kk * 32 + hi4 * 8];
#pragma unroll
    for (int n = 0; n < 2; ++n) {
      const bf16x8 b = *(const bf16x8*)&sWp[(n * 16 + lo16) * 72 + kk * 32 + hi4 * 8];
      ap[n] = __builtin_amdgcn_mfma_f32_16x16x32_bf16(a, b, ap[n], 0, 0, 0);
    }
  }
  const float bb = bbdy[0];
#pragma unroll
  for (int n = 0; n < 2; ++n) {
    const int col = n * 16 + lo16;
#pragma unroll
    for (int j = 0; j < 4; ++j) {
      const int m = m0 + R + hi4 * 4 + j;
      if (m < M_PTS) {
        if (col < KN) P[(size_t)m * KN + col] = f2bf(ap[n][j]);
        else if (col == KN) out[OFF_BDY + m] = ap[n][j] + bb;
      }
    }
  }
  __syncthreads();
  for (int i = tid; i < 512; i += 256) {
    const int r = i >> 3, u = i & 7;
    const int m = m0 + r;
    if (m < M_PTS) {
      *(bf16x8*)&Qg[(size_t)m * 64 + u * 8] = *(const bf16x8*)&sQ[r * 72 + u * 8];
      *(bf16x8*)&U[(size_t)m * 64 + u * 8] = *(const bf16x8*)&sX[r * 72 + u * 8];
    }
  }
  // neighbor / mask / vmask: quad per point (qq handles kq = qq*7 .. qq*7+6)
  {
    const bool is64 = nbr_is64(nbrv);
    const int r = tid >> 2, qq = tid & 3;
    const int m = m0 + r;
    unsigned vbits = 0;
    if (m < M_PTS) {
      const int c0 = coords[m * 3 + 0], c1 = coords[m * 3 + 1], c2 = coords[m * 3 + 2];
      const int kq0 = qq * 7;
      const int cnt = (qq == 3) ? 6 : 7;
#pragma unroll
      for (int t = 0; t < 7; ++t) {
        if (t < cnt) {
          const size_t ni = (size_t)m * KN + kq0 + t;
          const long long nk = nbr_at(nbrv, is64, ni);
          const int dx = coords[nk * 3 + 0] - c0;
          const int dy = coords[nk * 3 + 1] - c1;
          const int dz = coords[nk * 3 + 2] - c2;
          const int valid = (max(max(abs(dx), abs(dy)), abs(dz)) <= 1) ? 1 : 0;
          out[OFF_NBR + ni] = (float)nk;
          out[OFF_MASK + ni] = (float)valid;
          vbits |= (unsigned)valid << (kq0 + t);
        }
      }
    }
    vbits |= __shfl_xor(vbits, 1, 64);
    vbits |= __shfl_xor(vbits, 2, 64);
    if (qq == 0 && m < M_PTS) vmask[m] = vbits;
  }
}

// ---------------- k2: sparse phase A (common path = copy; rare full path), MFMA head ----------------
__global__ __launch_bounds__(256) void k2(const float* __restrict__ sem,
                                          const int* __restrict__ coords,
                                          const void* __restrict__ nbrv,
                                          const float* __restrict__ bout,
                                          const short* __restrict__ ws,
                                          const short* __restrict__ Qg,
                                          const short* __restrict__ U,
                                          const short* __restrict__ P,
                                          const unsigned int* __restrict__ vmask,
                                          float* __restrict__ out) {
  __shared__ short sW1[6656];  // [64][104]
  __shared__ short sW2[1664];  // [16][104]
  __shared__ short sS[6656];   // [64][104] s96 tile
  const int tid = threadIdx.x;
  {
    const bf16x8* a = (const bf16x8*)(ws + WS_W1);
    const bf16x8* b = (const bf16x8*)(ws + WS_W2);
    for (int i = tid; i < 832; i += 256) ((bf16x8*)sW1)[i] = a[i];
    for (int i = tid; i < 208; i += 256) ((bf16x8*)sW2)[i] = b[i];
  }
  const float* b2 = (const float*)(ws + WS_B2);
  const bool is64 = nbr_is64(nbrv);
  __syncthreads();

  const int lane = tid & 63, w = tid >> 6;
  const int hi4 = lane >> 4, lo16 = lane & 15;
  const int R = w * 16;
  const int m0 = blockIdx.x * 64;
  const int pbase = m0 + R;
  const int l31 = lane & 31;
  const int nvr = max(0, min(16, M_PTS - pbase));   // rows this wave owns

  // complex-point ballot (popcount>1 -> needs full attention path)
  unsigned mym = 0;
  if (lane < nvr) mym = vmask[pbase + lane];
  const unsigned long long cb = __ballot(__popc(mym) > 1);

  // common path: affinity = [1,0,...,0]
  const int naff = nvr * KN;
#pragma unroll
  for (int it = 0; it < 7; ++it) {
    const int idx = it * 64 + lane;
    if (idx < naff) {
      const int p = idx / KN;
      if (!((cb >> p) & 1))
        out[OFF_AFF + (size_t)pbase * KN + idx] = (idx - p * KN == 0) ? 1.f : 0.f;
    }
  }
  // common path: sS row = 2*sem[m] (coalesced f4 loads over 16 consecutive rows)
  {
    const f4* semb = (const f4*)(sem + (size_t)pbase * CS);
    const int nf4 = nvr * 24;
#pragma unroll
    for (int it = 0; it < 6; ++it) {
      const int idx = it * 64 + lane;
      if (idx < nf4) {
        const f4 v = semb[idx];
        const int linear = idx * 4, p = linear / 96, c = linear - p * 96;
        if (!((cb >> p) & 1)) {
          s16x4 st;
          st[0] = f2bf(2.f * v.x); st[1] = f2bf(2.f * v.y);
          st[2] = f2bf(2.f * v.z); st[3] = f2bf(2.f * v.w);
          *(s16x4*)&sS[(R + p) * 104 + c] = st;
        }
      }
    }
  }
  // rare path: full gather + dot + softmax + weighted sem sum
  unsigned long long cbl = cb;
  while (cbl) {
    const int p = __ffsll(cbl) - 1; cbl &= cbl - 1;
    const int m = pbase + p;
    int nk = 0, vf = 0, pidx = 13;
    if (lane < KN) {
      nk = (int)nbr_at(nbrv, is64, (size_t)m * KN + lane);
      const int dx = coords[nk * 3 + 0] - coords[m * 3 + 0];
      const int dy = coords[nk * 3 + 1] - coords[m * 3 + 1];
      const int dz = coords[nk * 3 + 2] - coords[m * 3 + 2];
      vf = (max(max(abs(dx), abs(dy)), abs(dz)) <= 1) ? 1 : 0;
      pidx = vf ? ((dx + 1) * 9 + (dy + 1) * 3 + (dz + 1)) : 13;
    }
    const float pval = (lane < KN) ? bf2f((unsigned short)P[(size_t)m * KN + pidx]) : 0.f;
    const float uv = bf2f((unsigned short)U[(size_t)m * 64 + lane]);
    float lg = -10000.f;
    unsigned long long vb = __ballot(vf != 0);
    while (vb) {
      const int k = __ffsll(vb) - 1; vb &= vb - 1;
      const int nn = __shfl(nk, k, 64);
      float dd = bf2f((unsigned short)Qg[(size_t)nn * 64 + lane]) * uv;
#pragma unroll
      for (int o = 1; o < 64; o <<= 1) dd += __shfl_xor(dd, o, 64);
      const float pv = __shfl(pval, k, 64);
      if (lane == k) lg = (dd + pv) * 0.125f;
    }
    float mx = lg;
#pragma unroll
    for (int o = 1; o < 32; o <<= 1) mx = fmaxf(mx, __shfl_xor(mx, o, 64));
    const float e = (lane < KN) ? __expf(lg - mx) : 0.f;
    float ssum = e;
#pragma unroll
    for (int o = 1; o < 32; o <<= 1) ssum += __shfl_xor(ssum, o, 64);
    const float aa = e / ssum;
    if (lane < KN) out[OFF_AFF + (size_t)m * KN + lane] = aa;
    float slo = sem[(size_t)m * CS + lane];
    float shi = sem[(size_t)m * CS + 64 + l31];
    unsigned long long ab = __ballot(lane < KN && aa > 0.f);
    while (ab) {
      const int k = __ffsll(ab) - 1; ab &= ab - 1;
      const float ak = __shfl(aa, k, 64);
      const int nn = __shfl(nk, k, 64);
      slo = fmaf(ak, sem[(size_t)nn * CS + lane], slo);
      shi = fmaf(ak, sem[(size_t)nn * CS + 64 + l31], shi);
    }
    sS[(R + p) * 104 + lane] = f2bf(slo);
    if (lane < 32) sS[(R + p) * 104 + 64 + lane] = f2bf(shi);
  }
  __syncthreads();

  // phase B: rf = S@W1 + bout ; logits = S@W2 + b2
  f32x4 ar[4] = {};
  f32x4 al = {};
#pragma unroll
  for (int kk = 0; kk < 3; ++kk) {
    const bf16x8 a = *(const bf16x8*)&sS[(R + lo16) * 104 + kk * 32 + hi4 * 8];
#pragma unroll
    for (int n = 0; n < 4; ++n) {
      const bf16x8 b = *(const bf16x8*)&sW1[(n * 16 + lo16) * 104 + kk * 32 + hi4 * 8];
      ar[n] = __builtin_amdgcn_mfma_f32_16x16x32_bf16(a, b, ar[n], 0, 0, 0);
    }
    const bf16x8 b = *(const bf16x8*)&sW2[lo16 * 104 + kk * 32 + hi4 * 8];
    al = __builtin_amdgcn_mfma_f32_16x16x32_bf16(a, b, al, 0, 0, 0);
  }
#pragma unroll
  for (int n = 0; n < 4; ++n) {
    const float bo = bout[n * 16 + lo16];
#pragma unroll
    for (int j = 0; j < 4; ++j) {
      const int m = m0 + R + hi4 * 4 + j;
      if (m < M_PTS) out[OFF_RF + (size_t)m * 64 + n * 16 + lo16] = ar[n][j] + bo;
    }
  }
  {
    const float bc = (lo16 < NC) ? b2[lo16] : 0.f;
#pragma unroll
    for (int j = 0; j < 4; ++j) {
      const int m = m0 + R + hi4 * 4 + j;
      if (m < M_PTS && lo16 < NC) out[OFF_LOGITS + (size_t)m * NC + lo16] = al[j] + bc;
    }
  }
}

extern "C" void kernel_launch(void* const* d_in, const int* in_sizes, int n_in,
                              void* d_out, int out_size, void* d_ws, size_t ws_size,
                              hipStream_t stream) {
  const float* geo = (const float*)d_in[0];
  const float* sem = (const float*)d_in[1];
  const int* coords = (const int*)d_in[2];
  const void* nbrv = (const void*)d_in[3];
  const float* Wgeo = (const float*)d_in[4];
  const float* gamma = (const float*)d_in[5];
  const float* beta = (const float*)d_in[6];
  const float* Wbdy = (const float*)d_in[7];
  const float* bbdy = (const float*)d_in[8];
  const float* Wq = (const float*)d_in[9];
  const float* Wk = (const float*)d_in[10];
  const float* Wv = (const float*)d_in[11];
  const float* pos = (const float*)d_in[12];
  const float* Wout = (const float*)d_in[13];
  const float* bout = (const float*)d_in[14];
  const float* Wcls = (const float*)d_in[15];
  const float* bcls = (const float*)d_in[16];

  short* ws = (short*)d_ws;
  short* Qg = ws + WS_QG;
  short* U = ws + WS_U;
  short* P = ws + WS_P;
  unsigned int* vmask = (unsigned int*)(ws + WS_VM);
  float* out = (float*)d_out;

  const int blocks = (M_PTS + 63) / 64;  // 1563
  k0<<<38, 256, 0, stream>>>(Wgeo, Wbdy, Wq, Wk, Wv, pos, Wout, bout, Wcls, bcls, ws);
  k1<<<blocks, 256, 0, stream>>>(geo, coords, nbrv, gamma, beta, bbdy, ws, Qg, U, P, vmask, out);
  k2<<<blocks, 256, 0, stream>>>(sem, coords, nbrv, bout, ws, Qg, U, P, vmask, out);
}